// Round 1
// baseline (106.024 us; speedup 1.0000x reference)
//
#include <hip/hip_runtime.h>
#include <math.h>

#define HDIM 128
#define EPSV 1e-5f
#define TOLV 1e-7f
#define MINSCORE 0.1f

// ---------------------------------------------------------------------------
// Stage 1: attention GCN (scalar, all nodes/edges)
// ---------------------------------------------------------------------------

__global__ void k_init(const float* __restrict__ x, const float* __restrict__ Wa,
                       float* __restrict__ deg1, float* __restrict__ degk,
                       float* __restrict__ hA, float* __restrict__ agg1,
                       int* __restrict__ slot, int* __restrict__ counters, int N) {
    if (blockIdx.x == 0 && threadIdx.x == 0) { counters[0] = 0; counters[1] = 0; }
    int stride = gridDim.x * blockDim.x;
    float wa0 = Wa[0], wa1 = Wa[1];
    for (int i = blockIdx.x * blockDim.x + threadIdx.x; i < N; i += stride) {
        deg1[i] = 1.0f;           // self-loop
        degk[i] = 1.0f;           // self-loop (kept-subgraph degree)
        agg1[i] = 0.0f;
        slot[i] = -1;
        hA[i] = x[2 * i] * wa0 + x[2 * i + 1] * wa1;   // x @ W_attn
    }
}

__global__ void k_deg1(const int* __restrict__ dst, float* __restrict__ deg1, int E) {
    int stride = gridDim.x * blockDim.x;
    for (int e = blockIdx.x * blockDim.x + threadIdx.x; e < E; e += stride)
        atomicAdd(&deg1[dst[e]], 1.0f);
}

__global__ void k_attn_scatter(const int* __restrict__ src, const int* __restrict__ dst,
                               const float* __restrict__ hA, const float* __restrict__ deg1,
                               float* __restrict__ agg1, int E) {
    int stride = gridDim.x * blockDim.x;
    for (int e = blockIdx.x * blockDim.x + threadIdx.x; e < E; e += stride) {
        int s = src[e], d = dst[e];
        float nrm = rsqrtf(deg1[s]) * rsqrtf(deg1[d]);
        atomicAdd(&agg1[d], hA[s] * nrm);
    }
}

__global__ void k_attn_node(const float* __restrict__ hA, const float* __restrict__ deg1,
                            const float* __restrict__ agg1, const float* __restrict__ bA,
                            const float* __restrict__ wt, float* __restrict__ score, int N) {
    int stride = gridDim.x * blockDim.x;
    float b = bA[0], w = wt[0];
    for (int i = blockIdx.x * blockDim.x + threadIdx.x; i < N; i += stride)
        score[i] = (agg1[i] + hA[i] * (1.0f / deg1[i]) + b) * w;  // pre-softmax s
}

// ---------------------------------------------------------------------------
// Stage 2: per-graph softmax + keep mask + kept-node compaction
// One block per graph; nodes of graph g are [g*P, (g+1)*P) (batch = arange//P).
// ---------------------------------------------------------------------------

__global__ void k_softmax_keep(const float* __restrict__ x, float* __restrict__ score,
                               int* __restrict__ keep, int* __restrict__ slot,
                               int* __restrict__ keptIdx, int* __restrict__ counters,
                               float* __restrict__ hbuf, int P, int KMAX) {
    int g = blockIdx.x, t = threadIdx.x;
    int base = g * P;
    __shared__ float red[256];

    float m = -INFINITY;
    for (int j = t; j < P; j += 256) m = fmaxf(m, score[base + j]);
    red[t] = m; __syncthreads();
    for (int s = 128; s > 0; s >>= 1) { if (t < s) red[t] = fmaxf(red[t], red[t + s]); __syncthreads(); }
    m = red[0]; __syncthreads();

    float z = 0.0f;
    for (int j = t; j < P; j += 256) z += expf(score[base + j] - m);
    red[t] = z; __syncthreads();
    for (int s = 128; s > 0; s >>= 1) { if (t < s) red[t] += red[t + s]; __syncthreads(); }
    z = red[0];

    // max node has exp(0)=1 exactly -> smax = 1/z, matching the reference bitwise-ish
    float thr = fminf(1.0f / z - TOLV, MINSCORE);

    for (int j = t; j < P; j += 256) {
        int i = base + j;
        float sc = expf(score[i] - m) / z;
        score[i] = sc;
        int kp = sc > thr ? 1 : 0;
        keep[i] = kp;
        if (kp) {
            int pos = atomicAdd(&counters[0], 1);
            if (pos < KMAX) {
                keptIdx[pos] = i;
                slot[i] = pos;
                // layer-0 input: h0 = x * score (2 features), stored at stride HDIM
                hbuf[pos * HDIM + 0] = x[2 * i]     * sc;
                hbuf[pos * HDIM + 1] = x[2 * i + 1] * sc;
            }
        }
    }
}

// Active edges = both endpoints kept. Also accumulate kept-subgraph in-degree.
__global__ void k_active_edges(const int* __restrict__ src, const int* __restrict__ dst,
                               const int* __restrict__ keep, float* __restrict__ degk,
                               int* __restrict__ aSrc, int* __restrict__ aDst,
                               int* __restrict__ counters, int E, int EMAX) {
    int stride = gridDim.x * blockDim.x;
    for (int e = blockIdx.x * blockDim.x + threadIdx.x; e < E; e += stride) {
        int s = src[e], d = dst[e];
        if (keep[s] && keep[d]) {
            atomicAdd(&degk[d], 1.0f);
            int pos = atomicAdd(&counters[1], 1);
            if (pos < EMAX) { aSrc[pos] = s; aDst[pos] = d; }
        }
    }
}

// ---------------------------------------------------------------------------
// Stage 3: GCN layers on kept nodes only (K ~= 40 rows)
// ---------------------------------------------------------------------------

// t[j,:] = h[j,:] @ W  (inDim = 2 or 128); also zero agg row for this layer.
__global__ void k_matmul(const float* __restrict__ hbuf, const float* __restrict__ W,
                         float* __restrict__ tbuf, float* __restrict__ aggbuf,
                         const int* __restrict__ counters, int inDim, int KMAX) {
    __shared__ float hrow[HDIM];
    int K = counters[0]; if (K > KMAX) K = KMAX;
    int t = threadIdx.x;
    for (int j = blockIdx.x; j < K; j += gridDim.x) {
        if (t < inDim) hrow[t] = hbuf[j * HDIM + t];
        __syncthreads();
        float acc = 0.0f;
        for (int k = 0; k < inDim; ++k) acc += hrow[k] * W[k * HDIM + t];
        tbuf[j * HDIM + t] = acc;
        aggbuf[j * HDIM + t] = 0.0f;
        __syncthreads();
    }
}

// Scatter messages over active (kept-kept) edges.
__global__ void k_edge_agg(const int* __restrict__ aSrc, const int* __restrict__ aDst,
                           const int* __restrict__ slot, const float* __restrict__ degk,
                           const float* __restrict__ tbuf, float* __restrict__ aggbuf,
                           const int* __restrict__ counters, int EMAX) {
    int ec = counters[1]; if (ec > EMAX) ec = EMAX;
    int c = threadIdx.x;
    for (int e = blockIdx.x; e < ec; e += gridDim.x) {
        int s = aSrc[e], d = aDst[e];
        int ss = slot[s], sd = slot[d];
        if (ss < 0 || sd < 0) continue;
        float nrm = rsqrtf(degk[s]) * rsqrtf(degk[d]);
        atomicAdd(&aggbuf[sd * HDIM + c], tbuf[ss * HDIM + c] * nrm);
    }
}

// h_next = BN(relu(agg + t/deg + b))
__global__ void k_finish(const float* __restrict__ tbuf, const float* __restrict__ aggbuf,
                         const int* __restrict__ keptIdx, const float* __restrict__ degk,
                         const float* __restrict__ b, const float* __restrict__ gam,
                         const float* __restrict__ bet, const float* __restrict__ mu,
                         const float* __restrict__ var, float* __restrict__ hbuf,
                         const int* __restrict__ counters, int KMAX) {
    int K = counters[0]; if (K > KMAX) K = KMAX;
    int c = threadIdx.x;
    for (int j = blockIdx.x; j < K; j += gridDim.x) {
        int node = keptIdx[j];
        float v = aggbuf[j * HDIM + c] + tbuf[j * HDIM + c] * (1.0f / degk[node]) + b[c];
        v = fmaxf(v, 0.0f);
        v = (v - mu[c]) * (gam[c] * rsqrtf(var[c] + EPSV)) + bet[c];
        hbuf[j * HDIM + c] = v;
    }
}

// ---------------------------------------------------------------------------
// Stage 4: per-graph max-pool over kept nodes + 128->3 head + log_softmax
// ---------------------------------------------------------------------------

__global__ void k_pool_head(const float* __restrict__ hbuf, const int* __restrict__ keptIdx,
                            const int* __restrict__ counters, const int* __restrict__ batch,
                            const float* __restrict__ Wf, const float* __restrict__ bf,
                            float* __restrict__ out, int KMAX) {
    int g = blockIdx.x, c = threadIdx.x;
    int K = counters[0]; if (K > KMAX) K = KMAX;
    float p = -INFINITY;
    for (int j = 0; j < K; ++j) {
        int node = keptIdx[j];
        if (batch[node] == g) p = fmaxf(p, hbuf[j * HDIM + c]);
    }
    __shared__ float sh[3 * HDIM];
    for (int r = 0; r < 3; ++r) sh[r * HDIM + c] = p * Wf[c * 3 + r];
    __syncthreads();
    for (int s = 64; s > 0; s >>= 1) {
        if (c < s) for (int r = 0; r < 3; ++r) sh[r * HDIM + c] += sh[r * HDIM + c + s];
        __syncthreads();
    }
    if (c == 0) {
        float l0 = sh[0] + bf[0], l1 = sh[HDIM] + bf[1], l2 = sh[2 * HDIM] + bf[2];
        float mm = fmaxf(l0, fmaxf(l1, l2));
        float zz = expf(l0 - mm) + expf(l1 - mm) + expf(l2 - mm);
        float lz = logf(zz) + mm;
        out[g * 3 + 0] = l0 - lz;
        out[g * 3 + 1] = l1 - lz;
        out[g * 3 + 2] = l2 - lz;
    }
}

// ---------------------------------------------------------------------------

extern "C" void kernel_launch(void* const* d_in, const int* in_sizes, int n_in,
                              void* d_out, int out_size, void* d_ws, size_t ws_size,
                              hipStream_t stream) {
    const float* x      = (const float*)d_in[0];
    const int*   src    = (const int*)d_in[1];
    const int*   dst    = (const int*)d_in[2];
    const int*   batch  = (const int*)d_in[3];
    const float* W_attn = (const float*)d_in[5];
    const float* b_attn = (const float*)d_in[6];
    const float* w_topk = (const float*)d_in[7];
    const float* Ws[3]  = {(const float*)d_in[8],  (const float*)d_in[14], (const float*)d_in[20]};
    const float* bs[3]  = {(const float*)d_in[9],  (const float*)d_in[15], (const float*)d_in[21]};
    const float* gs[3]  = {(const float*)d_in[10], (const float*)d_in[16], (const float*)d_in[22]};
    const float* bes[3] = {(const float*)d_in[11], (const float*)d_in[17], (const float*)d_in[23]};
    const float* ms[3]  = {(const float*)d_in[12], (const float*)d_in[18], (const float*)d_in[24]};
    const float* vs[3]  = {(const float*)d_in[13], (const float*)d_in[19], (const float*)d_in[25]};
    const float* Wf     = (const float*)d_in[26];
    const float* bf     = (const float*)d_in[27];
    float* out = (float*)d_out;

    int N  = in_sizes[3];        // batch array length
    int E  = in_sizes[1];        // src length
    int Gn = out_size / 3;       // graphs
    int Pn = N / Gn;             // nodes per graph

    // ---- workspace layout ----
    char* w = (char*)d_ws;
    auto alloc = [&](size_t bytes) -> void* {
        void* p = (void*)w;
        w += (bytes + 255) & ~size_t(255);
        return p;
    };
    float* deg1    = (float*)alloc((size_t)N * 4);
    float* degk    = (float*)alloc((size_t)N * 4);
    float* hA      = (float*)alloc((size_t)N * 4);
    float* agg1    = (float*)alloc((size_t)N * 4);
    float* score   = (float*)alloc((size_t)N * 4);
    int*   keep    = (int*)alloc((size_t)N * 4);
    int*   slot    = (int*)alloc((size_t)N * 4);
    int*   counters= (int*)alloc(256);
    const int EMAX = 16384;
    int* aSrc = (int*)alloc((size_t)EMAX * 4);
    int* aDst = (int*)alloc((size_t)EMAX * 4);
    // remaining space -> compact node buffers (hbuf, tbuf, aggbuf) + keptIdx
    size_t used = (size_t)(w - (char*)d_ws);
    size_t rem  = (ws_size > used) ? ws_size - used : 0;
    int KMAX = (int)(rem / (4 + 3 * HDIM * 4 + 64));   // conservative per-row cost
    if (KMAX > 4096) KMAX = 4096;
    if (KMAX < 64)   KMAX = 64;                        // trust ws is at least ~9MB
    int* keptIdx  = (int*)alloc((size_t)KMAX * 4);
    float* hbuf   = (float*)alloc((size_t)KMAX * HDIM * 4);
    float* tbuf   = (float*)alloc((size_t)KMAX * HDIM * 4);
    float* aggbuf = (float*)alloc((size_t)KMAX * HDIM * 4);

    // ---- stage 1: attention GCN ----
    k_init<<<256, 256, 0, stream>>>(x, W_attn, deg1, degk, hA, agg1, slot, counters, N);
    k_deg1<<<1024, 256, 0, stream>>>(dst, deg1, E);
    k_attn_scatter<<<1024, 256, 0, stream>>>(src, dst, hA, deg1, agg1, E);
    k_attn_node<<<256, 256, 0, stream>>>(hA, deg1, agg1, b_attn, w_topk, score, N);

    // ---- stage 2: softmax + keep + compaction ----
    k_softmax_keep<<<Gn, 256, 0, stream>>>(x, score, keep, slot, keptIdx, counters, hbuf, Pn, KMAX);
    k_active_edges<<<1024, 256, 0, stream>>>(src, dst, keep, degk, aSrc, aDst, counters, E, EMAX);

    // ---- stage 3: three GCN+ReLU+BN layers on kept nodes ----
    for (int l = 0; l < 3; ++l) {
        int inDim = (l == 0) ? 2 : HDIM;
        k_matmul<<<128, HDIM, 0, stream>>>(hbuf, Ws[l], tbuf, aggbuf, counters, inDim, KMAX);
        k_edge_agg<<<128, HDIM, 0, stream>>>(aSrc, aDst, slot, degk, tbuf, aggbuf, counters, EMAX);
        k_finish<<<128, HDIM, 0, stream>>>(tbuf, aggbuf, keptIdx, degk, bs[l], gs[l], bes[l],
                                           ms[l], vs[l], hbuf, counters, KMAX);
    }

    // ---- stage 4: pool + head + log_softmax ----
    k_pool_head<<<Gn, HDIM, 0, stream>>>(hbuf, keptIdx, counters, batch, Wf, bf, out, KMAX);
}